// Round 5
// baseline (891.660 us; speedup 1.0000x reference)
//
#include <hip/hip_runtime.h>
#include <hip/hip_bf16.h>

typedef unsigned short u16;
typedef __bf16 bfx8 __attribute__((ext_vector_type(8)));
typedef float fx4 __attribute__((ext_vector_type(4)));
typedef unsigned short ushort8 __attribute__((ext_vector_type(8)));

#define DEV __device__ __forceinline__

static constexpr int Lq = 2048, Dq = 768, DIN = 1536, NST = 16;
static constexpr int NCH = 128, LC = 16;            // scan chunks: 128 x 16 = 2048
static constexpr int SCB = NCH * (DIN / 256);       // 768 scan blocks

DEV u16 f2bf(float x) {
    union { float f; unsigned u; } v; v.f = x;
    unsigned r = v.u + 0x7fff + ((v.u >> 16) & 1);
    return (u16)(r >> 16);
}
DEV float bf2f(u16 v) {
    union { unsigned u; float f; } w; w.u = ((unsigned)v) << 16; return w.f;
}
// async 16B global->LDS (wave-uniform LDS base + lane*16, per-lane global addr)
DEV void gll16(const u16* g, u16* l) {
    __builtin_amdgcn_global_load_lds(
        (const __attribute__((address_space(1))) unsigned int*)g,
        (__attribute__((address_space(3))) unsigned int*)l, 16, 0, 0);
}

// ---- software grid barrier (device-scope; co-residency guaranteed by launch_bounds) ----
DEV void softbar(unsigned* cnt, unsigned* flag, unsigned nblk) {
    __syncthreads();
    if (threadIdx.x == 0) {
        __threadfence();
        unsigned a = __hip_atomic_fetch_add(cnt, 1u, __ATOMIC_ACQ_REL, __HIP_MEMORY_SCOPE_AGENT);
        if (a == nblk - 1u) {
            __hip_atomic_store(flag, 1u, __ATOMIC_RELEASE, __HIP_MEMORY_SCOPE_AGENT);
        } else {
            while (__hip_atomic_load(flag, __ATOMIC_ACQUIRE, __HIP_MEMORY_SCOPE_AGENT) == 0u)
                __builtin_amdgcn_s_sleep(8);
        }
        __threadfence();
    }
    __syncthreads();
}

// ---------------- prep: 4x transpose+cast + rmsnorm + barrier init, one kernel ----------
struct TD { const float* src; u16* dst; int R, C, Rp, Cp, nbx, blk0; };

__global__ __launch_bounds__(256) void prep(TD t0, TD t1, TD t2, TD t3,
                                            const float* __restrict__ x,
                                            const float* __restrict__ nw,
                                            u16* __restrict__ xn,
                                            unsigned* __restrict__ bar) {
    __shared__ float tile[32][33];
    __shared__ float wsum[4];
    int b = blockIdx.x;
    if (b == 0 && threadIdx.x < 8) bar[threadIdx.x] = 0;   // re-init flags every call
    if (b < 3744) {
        TD td = t0;
        if (b >= t3.blk0) td = t3; else if (b >= t2.blk0) td = t2; else if (b >= t1.blk0) td = t1;
        int local = b - td.blk0;
        int c0 = (local % td.nbx) * 32, r0 = (local / td.nbx) * 32;
        int tx = threadIdx.x & 31, ty = threadIdx.x >> 5;   // 32 x 8
        #pragma unroll
        for (int i = ty; i < 32; i += 8) {
            int r = r0 + i, c = c0 + tx;
            tile[i][tx] = (r < td.R && c < td.C) ? td.src[(size_t)r * td.C + c] : 0.f;
        }
        __syncthreads();
        #pragma unroll
        for (int i = ty; i < 32; i += 8) {
            int c = c0 + i, r = r0 + tx;
            if (c < td.Cp && r < td.Rp) td.dst[(size_t)c * td.Rp + r] = f2bf(tile[tx][i]);
        }
    } else {
        int t = b - 3744;
        const float* row = x + (size_t)t * Dq;
        float ss = 0.f;
        for (int i = threadIdx.x; i < Dq; i += 256) { float a = row[i]; ss += a * a; }
        #pragma unroll
        for (int o = 32; o > 0; o >>= 1) ss += __shfl_xor(ss, o, 64);
        if ((threadIdx.x & 63) == 0) wsum[threadIdx.x >> 6] = ss;
        __syncthreads();
        ss = wsum[0] + wsum[1] + wsum[2] + wsum[3];
        float scale = rsqrtf(ss * (1.f / Dq) + 1e-5f);
        for (int i = threadIdx.x; i < Dq; i += 256)
            xn[(size_t)t * Dq + i] = f2bf(row[i] * scale * nw[i]);
    }
}

// ---------------- generic NT bf16 MFMA GEMM, BK=64, gll staging + XOR-16B swizzle -------
// A: M x K bf16 row-major. BT: N x K bf16 row-major.
// EPI 0: C=acc(+R). EPI 3: Cb=bf16(acc). EPI 4: Cb=bf16(softplus(acc+bias[col])).
// EPI 5: C=acc f32 AND if col<64 Cb[row*64+col]=bf16(acc).
template<int BM, int BN, int EPI>
__global__ __launch_bounds__(256) void gemm_nt(const u16* __restrict__ A, const u16* __restrict__ BT,
                                               float* __restrict__ C, u16* __restrict__ Cb,
                                               const float* __restrict__ R,
                                               const float* __restrict__ bias,
                                               int M, int N, int K) {
    constexpr int BK = 64;
    constexpr int WM = BM / 2, WN = BN / 2, MI = WM / 16, NI = WN / 16;
    __shared__ u16 As[BM * BK];
    __shared__ u16 Bs[BN * BK];
    const int tid = threadIdx.x, lane = tid & 63, wid = tid >> 6;
    const int wr = wid >> 1, wc = wid & 1;
    const int bm0 = blockIdx.y * BM, bn0 = blockIdx.x * BN;
    const int li = lane & 15, g = lane >> 4;

    fx4 acc[MI][NI];
    #pragma unroll
    for (int mi = 0; mi < MI; mi++)
        #pragma unroll
        for (int ni = 0; ni < NI; ni++)
            #pragma unroll
            for (int q = 0; q < 4; q++) acc[mi][ni][q] = 0.f;

    for (int kt = 0; kt < K; kt += BK) {
        // stage: chunk c (16B) -> LDS linear; global col16 pre-XORed so that
        // LDS(row, c16) holds global col16 = c16 ^ (row&7)  (involution, rule 21)
        #pragma unroll
        for (int i = 0; i < (BM * 8) / 256; i++) {
            int cb = i * 256 + wid * 64;
            int c = cb + lane;
            int row = c >> 3, c16 = (c & 7) ^ (row & 7);
            gll16(A + (size_t)(bm0 + row) * K + kt + c16 * 8, &As[cb * 8]);
        }
        #pragma unroll
        for (int i = 0; i < (BN * 8) / 256; i++) {
            int cb = i * 256 + wid * 64;
            int c = cb + lane;
            int row = c >> 3, c16 = (c & 7) ^ (row & 7);
            gll16(BT + (size_t)(bn0 + row) * K + kt + c16 * 8, &Bs[cb * 8]);
        }
        __syncthreads();
        bfx8 af[MI][2], bfr[NI][2];
        #pragma unroll
        for (int mi = 0; mi < MI; mi++) {
            int row = wr * WM + mi * 16 + li;
            #pragma unroll
            for (int ks = 0; ks < 2; ks++)
                af[mi][ks] = *(const bfx8*)&As[row * BK + (((ks * 4 + g) ^ (row & 7)) * 8)];
        }
        #pragma unroll
        for (int ni = 0; ni < NI; ni++) {
            int row = wc * WN + ni * 16 + li;
            #pragma unroll
            for (int ks = 0; ks < 2; ks++)
                bfr[ni][ks] = *(const bfx8*)&Bs[row * BK + (((ks * 4 + g) ^ (row & 7)) * 8)];
        }
        #pragma unroll
        for (int ks = 0; ks < 2; ks++)
            #pragma unroll
            for (int mi = 0; mi < MI; mi++)
                #pragma unroll
                for (int ni = 0; ni < NI; ni++)
                    acc[mi][ni] = __builtin_amdgcn_mfma_f32_16x16x32_bf16(
                        af[mi][ks], bfr[ni][ks], acc[mi][ni], 0, 0, 0);
        __syncthreads();
    }

    #pragma unroll
    for (int mi = 0; mi < MI; mi++)
        #pragma unroll
        for (int ni = 0; ni < NI; ni++)
            #pragma unroll
            for (int q = 0; q < 4; q++) {
                int row = bm0 + wr * WM + mi * 16 + g * 4 + q;
                int col = bn0 + wc * WN + ni * 16 + li;
                size_t idx = (size_t)row * N + col;
                float v = acc[mi][ni][q];
                if constexpr (EPI == 0) {
                    if (R) v += R[idx];
                    C[idx] = v;
                } else if constexpr (EPI == 3) {
                    Cb[idx] = f2bf(v);
                } else if constexpr (EPI == 4) {
                    v += bias[col];
                    Cb[idx] = f2bf((v > 20.f) ? v : log1pf(__expf(v)));
                } else if constexpr (EPI == 5) {
                    C[idx] = v;
                    if (col < 64) Cb[(size_t)row * 64 + col] = f2bf(v);
                }
            }
}

// ---------------- depthwise causal conv (K=4) + bias + SiLU, 8-wide bf16 ----------------
__global__ __launch_bounds__(256) void conv_silu(const u16* __restrict__ xrb,
                                                 const float* __restrict__ cw,
                                                 const float* __restrict__ cb,
                                                 u16* __restrict__ ubf) {
    int i = blockIdx.x * 256 + threadIdx.x;            // one 8-group
    int t = i / (DIN / 8), d8 = (i - t * (DIN / 8)) * 8;
    float acc[8];
    #pragma unroll
    for (int j = 0; j < 8; j++) acc[j] = cb[d8 + j];
    #pragma unroll
    for (int k = 0; k < 4; k++) {
        int tt = t - 3 + k;
        if (tt < 0) continue;
        ushort8 xv = *(const ushort8*)(xrb + (size_t)tt * (2 * DIN) + d8);
        #pragma unroll
        for (int j = 0; j < 8; j++) acc[j] = fmaf(bf2f(xv[j]), cw[k * DIN + d8 + j], acc[j]);
    }
    ushort8 o;
    #pragma unroll
    for (int j = 0; j < 8; j++) {
        float s = acc[j] / (1.f + __expf(-acc[j]));
        o[j] = f2bf(s);
    }
    *(ushort8*)(ubf + (size_t)i * 8) = o;
}

// ---------------- fused selective scan: p1 | gridbar | p2 | gridbar | p3 ----------------
// chA/chX layout: [n][chunk][d] -> all stores/loads lane-coalesced.
__global__ __launch_bounds__(256, 4) void scan_fused(
        const u16* __restrict__ deltab, const u16* __restrict__ ubf,
        const float* __restrict__ xdbl, const float* __restrict__ A_log,
        const float* __restrict__ Dp, const u16* __restrict__ xrb,
        float* __restrict__ chA, float* __restrict__ chX,
        unsigned* __restrict__ bar, u16* __restrict__ ybf) {
    const int c = blockIdx.x;                       // chunk
    const int d = blockIdx.y * 256 + threadIdx.x;   // channel
    const int fid = blockIdx.y * NCH + blockIdx.x;  // flat block id
    float An[NST];
    #pragma unroll
    for (int i = 0; i < 4; i++) {
        float4 a = *(const float4*)(A_log + (size_t)d * NST + i * 4);
        An[i * 4 + 0] = -__expf(a.x); An[i * 4 + 1] = -__expf(a.y);
        An[i * 4 + 2] = -__expf(a.z); An[i * 4 + 3] = -__expf(a.w);
    }
    // ---- phase A: local chunk scan ----
    float s[NST];
    #pragma unroll
    for (int n = 0; n < NST; n++) s[n] = 0.f;
    float dlr[LC], uur[LC], sdl = 0.f;
    const int t0 = c * LC;
    #pragma unroll
    for (int tt = 0; tt < LC; tt++) {
        int t = t0 + tt;
        float dl = bf2f(deltab[(size_t)t * DIN + d]);
        float uu = bf2f(ubf[(size_t)t * DIN + d]);
        dlr[tt] = dl; uur[tt] = uu;
        float dlu = dl * uu;
        #pragma unroll
        for (int i = 0; i < 4; i++) {
            float4 b = *(const float4*)(xdbl + (size_t)t * 128 + 48 + i * 4);
            float dA0 = __expf(dl * An[i*4+0]); s[i*4+0] = fmaf(dA0, s[i*4+0], dlu * b.x);
            float dA1 = __expf(dl * An[i*4+1]); s[i*4+1] = fmaf(dA1, s[i*4+1], dlu * b.y);
            float dA2 = __expf(dl * An[i*4+2]); s[i*4+2] = fmaf(dA2, s[i*4+2], dlu * b.z);
            float dA3 = __expf(dl * An[i*4+3]); s[i*4+3] = fmaf(dA3, s[i*4+3], dlu * b.w);
        }
        sdl += dl;
    }
    #pragma unroll
    for (int n = 0; n < NST; n++) {
        size_t idx = (size_t)n * (NCH * DIN) + (size_t)c * DIN + d;
        __hip_atomic_store(&chX[idx], s[n], __ATOMIC_RELAXED, __HIP_MEMORY_SCOPE_AGENT);
        __hip_atomic_store(&chA[idx], __expf(An[n] * sdl), __ATOMIC_RELAXED, __HIP_MEMORY_SCOPE_AGENT);
    }
    softbar(&bar[0], &bar[1], SCB);
    // ---- phase B: cross-chunk combine (96 of 768 blocks); init written into chA ----
    if (fid < 96) {
        int n = fid / 6, dblk = fid % 6;
        int dd = dblk * 256 + threadIdx.x;
        size_t base = (size_t)n * (NCH * DIN) + dd;
        float s2 = 0.f;
        for (int cc = 0; cc < NCH; cc++) {
            size_t idx = base + (size_t)cc * DIN;
            float a  = __hip_atomic_load(&chA[idx], __ATOMIC_RELAXED, __HIP_MEMORY_SCOPE_AGENT);
            float xv = __hip_atomic_load(&chX[idx], __ATOMIC_RELAXED, __HIP_MEMORY_SCOPE_AGENT);
            __hip_atomic_store(&chA[idx], s2, __ATOMIC_RELAXED, __HIP_MEMORY_SCOPE_AGENT);
            s2 = fmaf(a, s2, xv);
        }
    }
    softbar(&bar[2], &bar[3], SCB);
    // ---- phase C: rescan with init, n-reduce, gate ----
    #pragma unroll
    for (int n = 0; n < NST; n++) {
        size_t idx = (size_t)n * (NCH * DIN) + (size_t)c * DIN + d;
        s[n] = __hip_atomic_load(&chA[idx], __ATOMIC_RELAXED, __HIP_MEMORY_SCOPE_AGENT);
    }
    float Dpd = Dp[d];
    #pragma unroll
    for (int tt = 0; tt < LC; tt++) {
        int t = t0 + tt;
        float dl = dlr[tt], uu = uur[tt];
        float dlu = dl * uu;
        float p = 0.f;
        #pragma unroll
        for (int i = 0; i < 4; i++) {
            float4 b  = *(const float4*)(xdbl + (size_t)t * 128 + 48 + i * 4);
            float4 cc = *(const float4*)(xdbl + (size_t)t * 128 + 64 + i * 4);
            float dA0 = __expf(dl * An[i*4+0]); s[i*4+0] = fmaf(dA0, s[i*4+0], dlu * b.x); p = fmaf(s[i*4+0], cc.x, p);
            float dA1 = __expf(dl * An[i*4+1]); s[i*4+1] = fmaf(dA1, s[i*4+1], dlu * b.y); p = fmaf(s[i*4+1], cc.y, p);
            float dA2 = __expf(dl * An[i*4+2]); s[i*4+2] = fmaf(dA2, s[i*4+2], dlu * b.z); p = fmaf(s[i*4+2], cc.z, p);
            float dA3 = __expf(dl * An[i*4+3]); s[i*4+3] = fmaf(dA3, s[i*4+3], dlu * b.w); p = fmaf(s[i*4+3], cc.w, p);
        }
        float res = bf2f(xrb[(size_t)t * (2 * DIN) + DIN + d]);
        float y = fmaf(uu, Dpd, p) * (res / (1.f + __expf(-res)));
        ybf[(size_t)t * DIN + d] = f2bf(y);
    }
}

extern "C" void kernel_launch(void* const* d_in, const int* in_sizes, int n_in,
                              void* d_out, int out_size, void* d_ws, size_t ws_size,
                              hipStream_t stream) {
    const float* x      = (const float*)d_in[0];
    const float* norm_w = (const float*)d_in[1];
    const float* W_in   = (const float*)d_in[2];
    const float* conv_w = (const float*)d_in[3];
    const float* conv_b = (const float*)d_in[4];
    const float* W_x    = (const float*)d_in[5];
    const float* W_dt   = (const float*)d_in[6];
    const float* b_dt   = (const float*)d_in[7];
    const float* A_log  = (const float*)d_in[8];
    const float* Dp     = (const float*)d_in[9];
    const float* W_out  = (const float*)d_in[10];
    float* out = (float*)d_out;

    char* wp = (char*)d_ws;
    auto alloc = [&](size_t bytes) { char* p = wp; wp += (bytes + 255) & ~(size_t)255; return p; };
    u16*      WinT   = (u16*)alloc((size_t)3072 * 768 * 2);
    u16*      WoutT  = (u16*)alloc((size_t)768 * 1536 * 2);
    u16*      WxT    = (u16*)alloc((size_t)128 * 1536 * 2);
    u16*      WdtT   = (u16*)alloc((size_t)1536 * 64 * 2);
    u16*      xn     = (u16*)alloc((size_t)Lq * Dq * 2);
    u16*      xrb    = (u16*)alloc((size_t)Lq * 3072 * 2);
    u16*      ubf    = (u16*)alloc((size_t)Lq * DIN * 2);
    float*    xdbl   = (float*)alloc((size_t)Lq * 128 * 4);
    u16*      draw   = (u16*)alloc((size_t)Lq * 64 * 2);
    u16*      deltab = (u16*)alloc((size_t)Lq * DIN * 2);
    float*    chA    = (float*)alloc((size_t)NCH * DIN * NST * 4);
    float*    chX    = (float*)alloc((size_t)NCH * DIN * NST * 4);
    u16*      ybf    = (u16*)alloc((size_t)Lq * DIN * 2);
    unsigned* bar    = (unsigned*)alloc(256);
    (void)ws_size; (void)in_sizes; (void)n_in; (void)out_size;

    // 1. prep: weight transposes + rmsnorm + barrier-flag init
    TD t0{W_in,  WinT,  768, 3072,  768, 3072, 96,    0};
    TD t1{W_out, WoutT, 1536, 768, 1536,  768, 24, 2304};
    TD t2{W_x,   WxT,  1536,   80, 1536,  128,  4, 3456};
    TD t3{W_dt,  WdtT,   48, 1536,   64, 1536, 48, 3648};
    prep<<<3744 + Lq, 256, 0, stream>>>(t0, t1, t2, t3, x, norm_w, xn, bar);

    // 2. GEMM1: xn(2048x768) @ W_in -> xrb (bf16)
    gemm_nt<128, 128, 3><<<dim3(3072 / 128, Lq / 128), 256, 0, stream>>>(
        xn, WinT, nullptr, xrb, nullptr, nullptr, Lq, 3072, 768);

    // 3. depthwise conv + silu -> ubf
    conv_silu<<<(Lq * DIN / 8) / 256, 256, 0, stream>>>(xrb, conv_w, conv_b, ubf);

    // 4. GEMM2: ubf @ W_x(->128) -> xdbl f32 + draw bf16
    gemm_nt<64, 64, 5><<<dim3(128 / 64, Lq / 64), 256, 0, stream>>>(
        ubf, WxT, xdbl, draw, nullptr, nullptr, Lq, 128, DIN);

    // 5. delta GEMM (K=64, single K-step): softplus -> deltab
    gemm_nt<128, 128, 4><<<dim3(1536 / 128, Lq / 128), 256, 0, stream>>>(
        draw, WdtT, nullptr, deltab, nullptr, b_dt, Lq, DIN, 64);

    // 6. fused selective scan + gate -> ybf
    scan_fused<<<dim3(NCH, DIN / 256), 256, 0, stream>>>(
        deltab, ubf, xdbl, A_log, Dp, xrb, chA, chX, bar, ybf);

    // 7. GEMM3: ybf @ W_out + x -> out
    gemm_nt<128, 64, 0><<<dim3(Dq / 64, Lq / 128), 256, 0, stream>>>(
        ybf, WoutT, out, nullptr, x, nullptr, Lq, Dq, DIN);
}

// Round 6
// 230.867 us; speedup vs baseline: 3.8622x; 3.8622x over previous
//
#include <hip/hip_runtime.h>
#include <hip/hip_bf16.h>

typedef unsigned short u16;
typedef __bf16 bfx8 __attribute__((ext_vector_type(8)));
typedef float fx4 __attribute__((ext_vector_type(4)));
typedef unsigned short ushort8 __attribute__((ext_vector_type(8)));

#define DEV __device__ __forceinline__

static constexpr int Lq = 2048, Dq = 768, DIN = 1536, NST = 16;
static constexpr int NCH = 128, LC = 16;            // scan chunks: 128 x 16 = 2048

DEV u16 f2bf(float x) {
    union { float f; unsigned u; } v; v.f = x;
    unsigned r = v.u + 0x7fff + ((v.u >> 16) & 1);
    return (u16)(r >> 16);
}
DEV float bf2f(u16 v) {
    union { unsigned u; float f; } w; w.u = ((unsigned)v) << 16; return w.f;
}
// async 16B global->LDS (wave-uniform LDS base + lane*16, per-lane global addr)
DEV void gll16(const u16* g, u16* l) {
    __builtin_amdgcn_global_load_lds(
        (const __attribute__((address_space(1))) unsigned int*)g,
        (__attribute__((address_space(3))) unsigned int*)l, 16, 0, 0);
}

// ---------------- prep: 4x transpose+cast + rmsnorm, one kernel ----------
struct TD { const float* src; u16* dst; int R, C, Rp, Cp, nbx, blk0; };

__global__ __launch_bounds__(256) void prep(TD t0, TD t1, TD t2, TD t3,
                                            const float* __restrict__ x,
                                            const float* __restrict__ nw,
                                            u16* __restrict__ xn) {
    __shared__ float tile[32][33];
    __shared__ float wsum[4];
    int b = blockIdx.x;
    if (b < 3744) {
        TD td = t0;
        if (b >= t3.blk0) td = t3; else if (b >= t2.blk0) td = t2; else if (b >= t1.blk0) td = t1;
        int local = b - td.blk0;
        int c0 = (local % td.nbx) * 32, r0 = (local / td.nbx) * 32;
        int tx = threadIdx.x & 31, ty = threadIdx.x >> 5;   // 32 x 8
        #pragma unroll
        for (int i = ty; i < 32; i += 8) {
            int r = r0 + i, c = c0 + tx;
            tile[i][tx] = (r < td.R && c < td.C) ? td.src[(size_t)r * td.C + c] : 0.f;
        }
        __syncthreads();
        #pragma unroll
        for (int i = ty; i < 32; i += 8) {
            int c = c0 + i, r = r0 + tx;
            if (c < td.Cp && r < td.Rp) td.dst[(size_t)c * td.Rp + r] = f2bf(tile[tx][i]);
        }
    } else {
        int t = b - 3744;
        const float* row = x + (size_t)t * Dq;
        float ss = 0.f;
        for (int i = threadIdx.x; i < Dq; i += 256) { float a = row[i]; ss += a * a; }
        #pragma unroll
        for (int o = 32; o > 0; o >>= 1) ss += __shfl_xor(ss, o, 64);
        if ((threadIdx.x & 63) == 0) wsum[threadIdx.x >> 6] = ss;
        __syncthreads();
        ss = wsum[0] + wsum[1] + wsum[2] + wsum[3];
        float scale = rsqrtf(ss * (1.f / Dq) + 1e-5f);
        for (int i = threadIdx.x; i < Dq; i += 256)
            xn[(size_t)t * Dq + i] = f2bf(row[i] * scale * nw[i]);
    }
}

// ---------------- generic NT bf16 MFMA GEMM, BK=64, gll staging + XOR-16B swizzle -------
// A: M x K bf16 row-major. BT: N x K bf16 row-major.
// EPI 0: C=acc(+R). EPI 3: Cb=bf16(acc). EPI 4: Cb=bf16(softplus(acc+bias[col])).
// EPI 5: C=acc f32 AND if col<64 Cb[row*64+col]=bf16(acc).
template<int BM, int BN, int EPI>
__global__ __launch_bounds__(256) void gemm_nt(const u16* __restrict__ A, const u16* __restrict__ BT,
                                               float* __restrict__ C, u16* __restrict__ Cb,
                                               const float* __restrict__ R,
                                               const float* __restrict__ bias,
                                               int M, int N, int K) {
    constexpr int BK = 64;
    constexpr int WM = BM / 2, WN = BN / 2, MI = WM / 16, NI = WN / 16;
    __shared__ u16 As[BM * BK];
    __shared__ u16 Bs[BN * BK];
    const int tid = threadIdx.x, lane = tid & 63, wid = tid >> 6;
    const int wr = wid >> 1, wc = wid & 1;
    const int bm0 = blockIdx.y * BM, bn0 = blockIdx.x * BN;
    const int li = lane & 15, g = lane >> 4;

    fx4 acc[MI][NI];
    #pragma unroll
    for (int mi = 0; mi < MI; mi++)
        #pragma unroll
        for (int ni = 0; ni < NI; ni++)
            #pragma unroll
            for (int q = 0; q < 4; q++) acc[mi][ni][q] = 0.f;

    for (int kt = 0; kt < K; kt += BK) {
        // stage: chunk c (16B) -> LDS linear; global col16 pre-XORed so that
        // LDS(row, c16) holds global col16 = c16 ^ (row&7)  (involution, rule 21)
        #pragma unroll
        for (int i = 0; i < (BM * 8) / 256; i++) {
            int cb = i * 256 + wid * 64;
            int c = cb + lane;
            int row = c >> 3, c16 = (c & 7) ^ (row & 7);
            gll16(A + (size_t)(bm0 + row) * K + kt + c16 * 8, &As[cb * 8]);
        }
        #pragma unroll
        for (int i = 0; i < (BN * 8) / 256; i++) {
            int cb = i * 256 + wid * 64;
            int c = cb + lane;
            int row = c >> 3, c16 = (c & 7) ^ (row & 7);
            gll16(BT + (size_t)(bn0 + row) * K + kt + c16 * 8, &Bs[cb * 8]);
        }
        __syncthreads();
        bfx8 af[MI][2], bfr[NI][2];
        #pragma unroll
        for (int mi = 0; mi < MI; mi++) {
            int row = wr * WM + mi * 16 + li;
            #pragma unroll
            for (int ks = 0; ks < 2; ks++)
                af[mi][ks] = *(const bfx8*)&As[row * BK + (((ks * 4 + g) ^ (row & 7)) * 8)];
        }
        #pragma unroll
        for (int ni = 0; ni < NI; ni++) {
            int row = wc * WN + ni * 16 + li;
            #pragma unroll
            for (int ks = 0; ks < 2; ks++)
                bfr[ni][ks] = *(const bfx8*)&Bs[row * BK + (((ks * 4 + g) ^ (row & 7)) * 8)];
        }
        #pragma unroll
        for (int ks = 0; ks < 2; ks++)
            #pragma unroll
            for (int mi = 0; mi < MI; mi++)
                #pragma unroll
                for (int ni = 0; ni < NI; ni++)
                    acc[mi][ni] = __builtin_amdgcn_mfma_f32_16x16x32_bf16(
                        af[mi][ks], bfr[ni][ks], acc[mi][ni], 0, 0, 0);
        __syncthreads();
    }

    #pragma unroll
    for (int mi = 0; mi < MI; mi++)
        #pragma unroll
        for (int ni = 0; ni < NI; ni++)
            #pragma unroll
            for (int q = 0; q < 4; q++) {
                int row = bm0 + wr * WM + mi * 16 + g * 4 + q;
                int col = bn0 + wc * WN + ni * 16 + li;
                size_t idx = (size_t)row * N + col;
                float v = acc[mi][ni][q];
                if constexpr (EPI == 0) {
                    if (R) v += R[idx];
                    C[idx] = v;
                } else if constexpr (EPI == 3) {
                    Cb[idx] = f2bf(v);
                } else if constexpr (EPI == 4) {
                    v += bias[col];
                    Cb[idx] = f2bf((v > 20.f) ? v : log1pf(__expf(v)));
                } else if constexpr (EPI == 5) {
                    C[idx] = v;
                    if (col < 64) Cb[(size_t)row * 64 + col] = f2bf(v);
                }
            }
}

// ---------------- depthwise causal conv (K=4) + bias + SiLU, 8-wide bf16 ----------------
__global__ __launch_bounds__(256) void conv_silu(const u16* __restrict__ xrb,
                                                 const float* __restrict__ cw,
                                                 const float* __restrict__ cb,
                                                 u16* __restrict__ ubf) {
    int i = blockIdx.x * 256 + threadIdx.x;            // one 8-group
    int t = i / (DIN / 8), d8 = (i - t * (DIN / 8)) * 8;
    float acc[8];
    #pragma unroll
    for (int j = 0; j < 8; j++) acc[j] = cb[d8 + j];
    #pragma unroll
    for (int k = 0; k < 4; k++) {
        int tt = t - 3 + k;
        if (tt < 0) continue;
        ushort8 xv = *(const ushort8*)(xrb + (size_t)tt * (2 * DIN) + d8);
        #pragma unroll
        for (int j = 0; j < 8; j++) acc[j] = fmaf(bf2f(xv[j]), cw[k * DIN + d8 + j], acc[j]);
    }
    ushort8 o;
    #pragma unroll
    for (int j = 0; j < 8; j++) {
        float s = acc[j] / (1.f + __expf(-acc[j]));
        o[j] = f2bf(s);
    }
    *(ushort8*)(ubf + (size_t)i * 8) = o;
}

// ---------------- selective scan, 3-pass chunked; chA/chX layout [n][chunk][d] ----------
// pass 1: local chunk scan from 0; store end-state (chX) and analytic A-product (chA).
__global__ __launch_bounds__(256) void scan_p1(const u16* __restrict__ deltab, const u16* __restrict__ ubf,
                                               const float* __restrict__ xdbl, const float* __restrict__ A_log,
                                               float* __restrict__ chA, float* __restrict__ chX) {
    const int c = blockIdx.x;
    const int d = blockIdx.y * 256 + threadIdx.x;
    float An[NST];
    #pragma unroll
    for (int i = 0; i < 4; i++) {
        float4 a = *(const float4*)(A_log + (size_t)d * NST + i * 4);
        An[i * 4 + 0] = -__expf(a.x); An[i * 4 + 1] = -__expf(a.y);
        An[i * 4 + 2] = -__expf(a.z); An[i * 4 + 3] = -__expf(a.w);
    }
    float s[NST];
    #pragma unroll
    for (int n = 0; n < NST; n++) s[n] = 0.f;
    float sdl = 0.f;
    const int t0 = c * LC;
    #pragma unroll
    for (int tt = 0; tt < LC; tt++) {
        int t = t0 + tt;
        float dl = bf2f(deltab[(size_t)t * DIN + d]);
        float uu = bf2f(ubf[(size_t)t * DIN + d]);
        float dlu = dl * uu;
        #pragma unroll
        for (int i = 0; i < 4; i++) {
            float4 b = *(const float4*)(xdbl + (size_t)t * 128 + 48 + i * 4);
            float dA0 = __expf(dl * An[i*4+0]); s[i*4+0] = fmaf(dA0, s[i*4+0], dlu * b.x);
            float dA1 = __expf(dl * An[i*4+1]); s[i*4+1] = fmaf(dA1, s[i*4+1], dlu * b.y);
            float dA2 = __expf(dl * An[i*4+2]); s[i*4+2] = fmaf(dA2, s[i*4+2], dlu * b.z);
            float dA3 = __expf(dl * An[i*4+3]); s[i*4+3] = fmaf(dA3, s[i*4+3], dlu * b.w);
        }
        sdl += dl;
    }
    #pragma unroll
    for (int n = 0; n < NST; n++) {
        size_t idx = (size_t)n * (NCH * DIN) + (size_t)c * DIN + d;
        chX[idx] = s[n];
        chA[idx] = __expf(An[n] * sdl);
    }
}

// pass 2: cross-chunk serial combine per (n,d); chunk-initial state written into chA.
__global__ __launch_bounds__(256) void scan_p2(float* __restrict__ chA, const float* __restrict__ chX) {
    int fid = blockIdx.x;                 // 96 blocks: n = fid/6, dblk = fid%6
    int n = fid / 6, dd = (fid % 6) * 256 + threadIdx.x;
    size_t base = (size_t)n * (NCH * DIN) + dd;
    float s2 = 0.f;
    for (int cc = 0; cc < NCH; cc++) {
        size_t idx = base + (size_t)cc * DIN;
        float a = chA[idx], xv = chX[idx];
        chA[idx] = s2;                    // becomes init-state for chunk cc
        s2 = fmaf(a, s2, xv);
    }
}

// pass 3: rescan with init (in chA), in-register n-reduction, gate -> ybf.
__global__ __launch_bounds__(256) void scan_p3(const u16* __restrict__ deltab, const u16* __restrict__ ubf,
                                               const float* __restrict__ xdbl, const float* __restrict__ A_log,
                                               const float* __restrict__ init, const float* __restrict__ Dp,
                                               const u16* __restrict__ xrb, u16* __restrict__ ybf) {
    const int c = blockIdx.x;
    const int d = blockIdx.y * 256 + threadIdx.x;
    float An[NST];
    #pragma unroll
    for (int i = 0; i < 4; i++) {
        float4 a = *(const float4*)(A_log + (size_t)d * NST + i * 4);
        An[i * 4 + 0] = -__expf(a.x); An[i * 4 + 1] = -__expf(a.y);
        An[i * 4 + 2] = -__expf(a.z); An[i * 4 + 3] = -__expf(a.w);
    }
    float s[NST];
    #pragma unroll
    for (int n = 0; n < NST; n++)
        s[n] = init[(size_t)n * (NCH * DIN) + (size_t)c * DIN + d];
    float Dpd = Dp[d];
    const int t0 = c * LC;
    #pragma unroll
    for (int tt = 0; tt < LC; tt++) {
        int t = t0 + tt;
        float dl = bf2f(deltab[(size_t)t * DIN + d]);
        float uu = bf2f(ubf[(size_t)t * DIN + d]);
        float dlu = dl * uu;
        float p = 0.f;
        #pragma unroll
        for (int i = 0; i < 4; i++) {
            float4 b  = *(const float4*)(xdbl + (size_t)t * 128 + 48 + i * 4);
            float4 cc = *(const float4*)(xdbl + (size_t)t * 128 + 64 + i * 4);
            float dA0 = __expf(dl * An[i*4+0]); s[i*4+0] = fmaf(dA0, s[i*4+0], dlu * b.x); p = fmaf(s[i*4+0], cc.x, p);
            float dA1 = __expf(dl * An[i*4+1]); s[i*4+1] = fmaf(dA1, s[i*4+1], dlu * b.y); p = fmaf(s[i*4+1], cc.y, p);
            float dA2 = __expf(dl * An[i*4+2]); s[i*4+2] = fmaf(dA2, s[i*4+2], dlu * b.z); p = fmaf(s[i*4+2], cc.z, p);
            float dA3 = __expf(dl * An[i*4+3]); s[i*4+3] = fmaf(dA3, s[i*4+3], dlu * b.w); p = fmaf(s[i*4+3], cc.w, p);
        }
        float res = bf2f(xrb[(size_t)t * (2 * DIN) + DIN + d]);
        float y = fmaf(uu, Dpd, p) * (res / (1.f + __expf(-res)));
        ybf[(size_t)t * DIN + d] = f2bf(y);
    }
}

extern "C" void kernel_launch(void* const* d_in, const int* in_sizes, int n_in,
                              void* d_out, int out_size, void* d_ws, size_t ws_size,
                              hipStream_t stream) {
    const float* x      = (const float*)d_in[0];
    const float* norm_w = (const float*)d_in[1];
    const float* W_in   = (const float*)d_in[2];
    const float* conv_w = (const float*)d_in[3];
    const float* conv_b = (const float*)d_in[4];
    const float* W_x    = (const float*)d_in[5];
    const float* W_dt   = (const float*)d_in[6];
    const float* b_dt   = (const float*)d_in[7];
    const float* A_log  = (const float*)d_in[8];
    const float* Dp     = (const float*)d_in[9];
    const float* W_out  = (const float*)d_in[10];
    float* out = (float*)d_out;

    char* wp = (char*)d_ws;
    auto alloc = [&](size_t bytes) { char* p = wp; wp += (bytes + 255) & ~(size_t)255; return p; };
    u16*      WinT   = (u16*)alloc((size_t)3072 * 768 * 2);
    u16*      WoutT  = (u16*)alloc((size_t)768 * 1536 * 2);
    u16*      WxT    = (u16*)alloc((size_t)128 * 1536 * 2);
    u16*      WdtT   = (u16*)alloc((size_t)1536 * 64 * 2);
    u16*      xn     = (u16*)alloc((size_t)Lq * Dq * 2);
    u16*      xrb    = (u16*)alloc((size_t)Lq * 3072 * 2);
    u16*      ubf    = (u16*)alloc((size_t)Lq * DIN * 2);
    float*    xdbl   = (float*)alloc((size_t)Lq * 128 * 4);
    u16*      draw   = (u16*)alloc((size_t)Lq * 64 * 2);
    u16*      deltab = (u16*)alloc((size_t)Lq * DIN * 2);
    float*    chA    = (float*)alloc((size_t)NCH * DIN * NST * 4);
    float*    chX    = (float*)alloc((size_t)NCH * DIN * NST * 4);
    u16*      ybf    = (u16*)alloc((size_t)Lq * DIN * 2);
    (void)ws_size; (void)in_sizes; (void)n_in; (void)out_size;

    // 1. prep: weight transposes + rmsnorm
    TD t0{W_in,  WinT,  768, 3072,  768, 3072, 96,    0};
    TD t1{W_out, WoutT, 1536, 768, 1536,  768, 24, 2304};
    TD t2{W_x,   WxT,  1536,   80, 1536,  128,  4, 3456};
    TD t3{W_dt,  WdtT,   48, 1536,   64, 1536, 48, 3648};
    prep<<<3744 + Lq, 256, 0, stream>>>(t0, t1, t2, t3, x, norm_w, xn);

    // 2. GEMM1: xn(2048x768) @ W_in -> xrb (bf16)
    gemm_nt<128, 128, 3><<<dim3(3072 / 128, Lq / 128), 256, 0, stream>>>(
        xn, WinT, nullptr, xrb, nullptr, nullptr, Lq, 3072, 768);

    // 3. depthwise conv + silu -> ubf
    conv_silu<<<(Lq * DIN / 8) / 256, 256, 0, stream>>>(xrb, conv_w, conv_b, ubf);

    // 4. GEMM2: ubf @ W_x(->128) -> xdbl f32 + draw bf16
    gemm_nt<64, 64, 5><<<dim3(128 / 64, Lq / 64), 256, 0, stream>>>(
        ubf, WxT, xdbl, draw, nullptr, nullptr, Lq, 128, DIN);

    // 5. delta GEMM (K=64, single K-step): softplus -> deltab
    gemm_nt<128, 128, 4><<<dim3(1536 / 128, Lq / 128), 256, 0, stream>>>(
        draw, WdtT, nullptr, deltab, nullptr, b_dt, Lq, DIN, 64);

    // 6-8. selective scan (3-pass chunked, plain cached mem ops) + gate -> ybf
    scan_p1<<<dim3(NCH, DIN / 256), 256, 0, stream>>>(deltab, ubf, xdbl, A_log, chA, chX);
    scan_p2<<<96, 256, 0, stream>>>(chA, chX);
    scan_p3<<<dim3(NCH, DIN / 256), 256, 0, stream>>>(deltab, ubf, xdbl, A_log, chA, Dp, xrb, ybf);

    // 9. GEMM3: ybf @ W_out + x -> out
    gemm_nt<128, 64, 0><<<dim3(Dq / 64, Lq / 128), 256, 0, stream>>>(
        ybf, WoutT, out, nullptr, x, nullptr, Lq, Dq, DIN);
}

// Round 7
// 226.960 us; speedup vs baseline: 3.9287x; 1.0172x over previous
//
#include <hip/hip_runtime.h>
#include <hip/hip_bf16.h>

typedef unsigned short u16;
typedef __bf16 bfx8 __attribute__((ext_vector_type(8)));
typedef float fx4 __attribute__((ext_vector_type(4)));
typedef unsigned short ushort8 __attribute__((ext_vector_type(8)));

#define DEV __device__ __forceinline__

static constexpr int Lq = 2048, Dq = 768, DIN = 1536, NST = 16;
static constexpr int NCH = 64, LC = 32;            // scan chunks: 64 x 32 = 2048

DEV u16 f2bf(float x) {
    union { float f; unsigned u; } v; v.f = x;
    unsigned r = v.u + 0x7fff + ((v.u >> 16) & 1);
    return (u16)(r >> 16);
}
DEV float bf2f(u16 v) {
    union { unsigned u; float f; } w; w.u = ((unsigned)v) << 16; return w.f;
}
// async 16B global->LDS (wave-uniform LDS base + lane*16, per-lane global addr)
DEV void gll16(const u16* g, u16* l) {
    __builtin_amdgcn_global_load_lds(
        (const __attribute__((address_space(1))) unsigned int*)g,
        (__attribute__((address_space(3))) unsigned int*)l, 16, 0, 0);
}

// ---------------- prep: 4x transpose+cast + rmsnorm + xdbl zero-init ----------
struct TD { const float* src; u16* dst; int R, C, Rp, Cp, nbx, blk0; };

__global__ __launch_bounds__(256) void prep(TD t0, TD t1, TD t2, TD t3,
                                            const float* __restrict__ x,
                                            const float* __restrict__ nw,
                                            u16* __restrict__ xn,
                                            float* __restrict__ xdbl) {
    __shared__ float tile[32][33];
    __shared__ float wsum[4];
    int b = blockIdx.x;
    if (b < 3744) {
        TD td = t0;
        if (b >= t3.blk0) td = t3; else if (b >= t2.blk0) td = t2; else if (b >= t1.blk0) td = t1;
        int local = b - td.blk0;
        int c0 = (local % td.nbx) * 32, r0 = (local / td.nbx) * 32;
        int tx = threadIdx.x & 31, ty = threadIdx.x >> 5;   // 32 x 8
        #pragma unroll
        for (int i = ty; i < 32; i += 8) {
            int r = r0 + i, c = c0 + tx;
            tile[i][tx] = (r < td.R && c < td.C) ? td.src[(size_t)r * td.C + c] : 0.f;
        }
        __syncthreads();
        #pragma unroll
        for (int i = ty; i < 32; i += 8) {
            int c = c0 + i, r = r0 + tx;
            if (c < td.Cp && r < td.Rp) td.dst[(size_t)c * td.Rp + r] = f2bf(tile[tx][i]);
        }
    } else {
        int t = b - 3744;
        // zero xdbl row t (split-K GEMM2 accumulates into it atomically)
        if (threadIdx.x < 128) xdbl[(size_t)t * 128 + threadIdx.x] = 0.f;
        const float* row = x + (size_t)t * Dq;
        float ss = 0.f;
        for (int i = threadIdx.x; i < Dq; i += 256) { float a = row[i]; ss += a * a; }
        #pragma unroll
        for (int o = 32; o > 0; o >>= 1) ss += __shfl_xor(ss, o, 64);
        if ((threadIdx.x & 63) == 0) wsum[threadIdx.x >> 6] = ss;
        __syncthreads();
        ss = wsum[0] + wsum[1] + wsum[2] + wsum[3];
        float scale = rsqrtf(ss * (1.f / Dq) + 1e-5f);
        for (int i = threadIdx.x; i < Dq; i += 256)
            xn[(size_t)t * Dq + i] = f2bf(row[i] * scale * nw[i]);
    }
}

// ---------------- generic NT bf16 MFMA GEMM, BK=64, gll staging + XOR-16B swizzle -------
// A: M x K bf16 row-major (or, if AF32, Af: M x 128 f32, cols kt.. used). BT: N x K bf16.
// EPI 0: C=acc(+R). EPI 2: atomicAdd(C, acc). EPI 3: Cb=bf16(acc).
// EPI 4: Cb=bf16(softplus(acc+bias[col])).
template<int BM, int BN, int EPI, bool AF32 = false>
__global__ __launch_bounds__(256) void gemm_nt(const u16* __restrict__ A,
                                               const float* __restrict__ Af,
                                               const u16* __restrict__ BT,
                                               float* __restrict__ C, u16* __restrict__ Cb,
                                               const float* __restrict__ R,
                                               const float* __restrict__ bias,
                                               int M, int N, int K, int kLen) {
    constexpr int BK = 64;
    constexpr int WM = BM / 2, WN = BN / 2, MI = WM / 16, NI = WN / 16;
    __shared__ u16 As[BM * BK];
    __shared__ u16 Bs[BN * BK];
    const int tid = threadIdx.x, lane = tid & 63, wid = tid >> 6;
    const int wr = wid >> 1, wc = wid & 1;
    const int bm0 = blockIdx.y * BM, bn0 = blockIdx.x * BN;
    const int k0 = blockIdx.z * kLen;
    const int li = lane & 15, g = lane >> 4;

    fx4 acc[MI][NI];
    #pragma unroll
    for (int mi = 0; mi < MI; mi++)
        #pragma unroll
        for (int ni = 0; ni < NI; ni++)
            #pragma unroll
            for (int q = 0; q < 4; q++) acc[mi][ni][q] = 0.f;

    for (int kt = k0; kt < k0 + kLen; kt += BK) {
        // stage: 16B granule c -> LDS linear; global granule pre-XORed so that
        // LDS(row, j) holds global granule j^(row&7)  (involution, rule 21)
        if constexpr (AF32) {
            // A from f32 source (row stride 128 f32): reg-stage + cvt + ds_write,
            // same granule->swizzle mapping as the gll16 path.
            #pragma unroll
            for (int i = 0; i < (BM * 8) / 256; i++) {
                int c = i * 256 + tid;
                int row = c >> 3, g16 = (c & 7) ^ (row & 7);
                const float* src = Af + (size_t)(bm0 + row) * 128 + kt + g16 * 8;
                float4 a0 = *(const float4*)src;
                float4 a1 = *(const float4*)(src + 4);
                ushort8 o;
                o[0] = f2bf(a0.x); o[1] = f2bf(a0.y); o[2] = f2bf(a0.z); o[3] = f2bf(a0.w);
                o[4] = f2bf(a1.x); o[5] = f2bf(a1.y); o[6] = f2bf(a1.z); o[7] = f2bf(a1.w);
                *(ushort8*)(&As[c * 8]) = o;
            }
        } else {
            #pragma unroll
            for (int i = 0; i < (BM * 8) / 256; i++) {
                int cb = i * 256 + wid * 64;
                int c = cb + lane;
                int row = c >> 3, g16 = (c & 7) ^ (row & 7);
                gll16(A + (size_t)(bm0 + row) * K + kt + g16 * 8, &As[cb * 8]);
            }
        }
        #pragma unroll
        for (int i = 0; i < (BN * 8) / 256; i++) {
            int cb = i * 256 + wid * 64;
            int c = cb + lane;
            int row = c >> 3, g16 = (c & 7) ^ (row & 7);
            gll16(BT + (size_t)(bn0 + row) * K + kt + g16 * 8, &Bs[cb * 8]);
        }
        __syncthreads();
        bfx8 af[MI][2], bfr[NI][2];
        #pragma unroll
        for (int mi = 0; mi < MI; mi++) {
            int row = wr * WM + mi * 16 + li;
            #pragma unroll
            for (int ks = 0; ks < 2; ks++)
                af[mi][ks] = *(const bfx8*)&As[row * BK + (((ks * 4 + g) ^ (row & 7)) * 8)];
        }
        #pragma unroll
        for (int ni = 0; ni < NI; ni++) {
            int row = wc * WN + ni * 16 + li;
            #pragma unroll
            for (int ks = 0; ks < 2; ks++)
                bfr[ni][ks] = *(const bfx8*)&Bs[row * BK + (((ks * 4 + g) ^ (row & 7)) * 8)];
        }
        #pragma unroll
        for (int ks = 0; ks < 2; ks++)
            #pragma unroll
            for (int mi = 0; mi < MI; mi++)
                #pragma unroll
                for (int ni = 0; ni < NI; ni++)
                    acc[mi][ni] = __builtin_amdgcn_mfma_f32_16x16x32_bf16(
                        af[mi][ks], bfr[ni][ks], acc[mi][ni], 0, 0, 0);
        __syncthreads();
    }

    #pragma unroll
    for (int mi = 0; mi < MI; mi++)
        #pragma unroll
        for (int ni = 0; ni < NI; ni++)
            #pragma unroll
            for (int q = 0; q < 4; q++) {
                int row = bm0 + wr * WM + mi * 16 + g * 4 + q;
                int col = bn0 + wc * WN + ni * 16 + li;
                size_t idx = (size_t)row * N + col;
                float v = acc[mi][ni][q];
                if constexpr (EPI == 0) {
                    if (R) v += R[idx];
                    C[idx] = v;
                } else if constexpr (EPI == 2) {
                    atomicAdd(&C[idx], v);
                } else if constexpr (EPI == 3) {
                    Cb[idx] = f2bf(v);
                } else if constexpr (EPI == 4) {
                    v += bias[col];
                    Cb[idx] = f2bf((v > 20.f) ? v : log1pf(__expf(v)));
                }
            }
}

// ---------------- depthwise causal conv (K=4) + bias + SiLU, 8-wide bf16 ----------------
__global__ __launch_bounds__(256) void conv_silu(const u16* __restrict__ xrb,
                                                 const float* __restrict__ cw,
                                                 const float* __restrict__ cb,
                                                 u16* __restrict__ ubf) {
    int i = blockIdx.x * 256 + threadIdx.x;            // one 8-group
    int t = i / (DIN / 8), d8 = (i - t * (DIN / 8)) * 8;
    float acc[8];
    #pragma unroll
    for (int j = 0; j < 8; j++) acc[j] = cb[d8 + j];
    #pragma unroll
    for (int k = 0; k < 4; k++) {
        int tt = t - 3 + k;
        if (tt < 0) continue;
        ushort8 xv = *(const ushort8*)(xrb + (size_t)tt * (2 * DIN) + d8);
        #pragma unroll
        for (int j = 0; j < 8; j++) acc[j] = fmaf(bf2f(xv[j]), cw[k * DIN + d8 + j], acc[j]);
    }
    ushort8 o;
    #pragma unroll
    for (int j = 0; j < 8; j++) {
        float s = acc[j] / (1.f + __expf(-acc[j]));
        o[j] = f2bf(s);
    }
    *(ushort8*)(ubf + (size_t)i * 8) = o;
}

// ---------------- selective scan, 3-pass chunked; chA/chX layout [n][chunk][d] ----------
// pass 1: local chunk scan from 0; store end-state (chX) and analytic A-product (chA).
__global__ __launch_bounds__(256) void scan_p1(const u16* __restrict__ deltab, const u16* __restrict__ ubf,
                                               const float* __restrict__ xdbl, const float* __restrict__ A_log,
                                               float* __restrict__ chA, float* __restrict__ chX) {
    const int c = blockIdx.x;
    const int d = blockIdx.y * 256 + threadIdx.x;
    float An[NST];
    #pragma unroll
    for (int i = 0; i < 4; i++) {
        float4 a = *(const float4*)(A_log + (size_t)d * NST + i * 4);
        An[i * 4 + 0] = -__expf(a.x); An[i * 4 + 1] = -__expf(a.y);
        An[i * 4 + 2] = -__expf(a.z); An[i * 4 + 3] = -__expf(a.w);
    }
    float s[NST];
    #pragma unroll
    for (int n = 0; n < NST; n++) s[n] = 0.f;
    float sdl = 0.f;
    const int t0 = c * LC;
    for (int tt = 0; tt < LC; tt++) {
        int t = t0 + tt;
        float dl = bf2f(deltab[(size_t)t * DIN + d]);
        float uu = bf2f(ubf[(size_t)t * DIN + d]);
        float dlu = dl * uu;
        #pragma unroll
        for (int i = 0; i < 4; i++) {
            float4 b = *(const float4*)(xdbl + (size_t)t * 128 + 48 + i * 4);
            float dA0 = __expf(dl * An[i*4+0]); s[i*4+0] = fmaf(dA0, s[i*4+0], dlu * b.x);
            float dA1 = __expf(dl * An[i*4+1]); s[i*4+1] = fmaf(dA1, s[i*4+1], dlu * b.y);
            float dA2 = __expf(dl * An[i*4+2]); s[i*4+2] = fmaf(dA2, s[i*4+2], dlu * b.z);
            float dA3 = __expf(dl * An[i*4+3]); s[i*4+3] = fmaf(dA3, s[i*4+3], dlu * b.w);
        }
        sdl += dl;
    }
    #pragma unroll
    for (int n = 0; n < NST; n++) {
        size_t idx = (size_t)n * (NCH * DIN) + (size_t)c * DIN + d;
        chX[idx] = s[n];
        chA[idx] = __expf(An[n] * sdl);
    }
}

// pass 2: cross-chunk serial combine per (n,d); chunk-initial state written into chA.
__global__ __launch_bounds__(256) void scan_p2(float* __restrict__ chA, const float* __restrict__ chX) {
    int fid = blockIdx.x;                 // 96 blocks: n = fid/6, dblk = fid%6
    int n = fid / 6, dd = (fid % 6) * 256 + threadIdx.x;
    size_t base = (size_t)n * (NCH * DIN) + dd;
    float s2 = 0.f;
    for (int cc = 0; cc < NCH; cc++) {
        size_t idx = base + (size_t)cc * DIN;
        float a = chA[idx], xv = chX[idx];
        chA[idx] = s2;                    // becomes init-state for chunk cc
        s2 = fmaf(a, s2, xv);
    }
}

// pass 3: rescan with init (in chA), in-register n-reduction, gate -> ybf.
__global__ __launch_bounds__(256) void scan_p3(const u16* __restrict__ deltab, const u16* __restrict__ ubf,
                                               const float* __restrict__ xdbl, const float* __restrict__ A_log,
                                               const float* __restrict__ init, const float* __restrict__ Dp,
                                               const u16* __restrict__ xrb, u16* __restrict__ ybf) {
    const int c = blockIdx.x;
    const int d = blockIdx.y * 256 + threadIdx.x;
    float An[NST];
    #pragma unroll
    for (int i = 0; i < 4; i++) {
        float4 a = *(const float4*)(A_log + (size_t)d * NST + i * 4);
        An[i * 4 + 0] = -__expf(a.x); An[i * 4 + 1] = -__expf(a.y);
        An[i * 4 + 2] = -__expf(a.z); An[i * 4 + 3] = -__expf(a.w);
    }
    float s[NST];
    #pragma unroll
    for (int n = 0; n < NST; n++)
        s[n] = init[(size_t)n * (NCH * DIN) + (size_t)c * DIN + d];
    float Dpd = Dp[d];
    const int t0 = c * LC;
    for (int tt = 0; tt < LC; tt++) {
        int t = t0 + tt;
        float dl = bf2f(deltab[(size_t)t * DIN + d]);
        float uu = bf2f(ubf[(size_t)t * DIN + d]);
        float dlu = dl * uu;
        float p = 0.f;
        #pragma unroll
        for (int i = 0; i < 4; i++) {
            float4 b  = *(const float4*)(xdbl + (size_t)t * 128 + 48 + i * 4);
            float4 cc = *(const float4*)(xdbl + (size_t)t * 128 + 64 + i * 4);
            float dA0 = __expf(dl * An[i*4+0]); s[i*4+0] = fmaf(dA0, s[i*4+0], dlu * b.x); p = fmaf(s[i*4+0], cc.x, p);
            float dA1 = __expf(dl * An[i*4+1]); s[i*4+1] = fmaf(dA1, s[i*4+1], dlu * b.y); p = fmaf(s[i*4+1], cc.y, p);
            float dA2 = __expf(dl * An[i*4+2]); s[i*4+2] = fmaf(dA2, s[i*4+2], dlu * b.z); p = fmaf(s[i*4+2], cc.z, p);
            float dA3 = __expf(dl * An[i*4+3]); s[i*4+3] = fmaf(dA3, s[i*4+3], dlu * b.w); p = fmaf(s[i*4+3], cc.w, p);
        }
        float res = bf2f(xrb[(size_t)t * (2 * DIN) + DIN + d]);
        float y = fmaf(uu, Dpd, p) * (res / (1.f + __expf(-res)));
        ybf[(size_t)t * DIN + d] = f2bf(y);
    }
}

extern "C" void kernel_launch(void* const* d_in, const int* in_sizes, int n_in,
                              void* d_out, int out_size, void* d_ws, size_t ws_size,
                              hipStream_t stream) {
    const float* x      = (const float*)d_in[0];
    const float* norm_w = (const float*)d_in[1];
    const float* W_in   = (const float*)d_in[2];
    const float* conv_w = (const float*)d_in[3];
    const float* conv_b = (const float*)d_in[4];
    const float* W_x    = (const float*)d_in[5];
    const float* W_dt   = (const float*)d_in[6];
    const float* b_dt   = (const float*)d_in[7];
    const float* A_log  = (const float*)d_in[8];
    const float* Dp     = (const float*)d_in[9];
    const float* W_out  = (const float*)d_in[10];
    float* out = (float*)d_out;

    char* wp = (char*)d_ws;
    auto alloc = [&](size_t bytes) { char* p = wp; wp += (bytes + 255) & ~(size_t)255; return p; };
    u16*      WinT   = (u16*)alloc((size_t)3072 * 768 * 2);
    u16*      WoutT  = (u16*)alloc((size_t)768 * 1536 * 2);
    u16*      WxT    = (u16*)alloc((size_t)128 * 1536 * 2);
    u16*      WdtT   = (u16*)alloc((size_t)1536 * 64 * 2);
    u16*      xn     = (u16*)alloc((size_t)Lq * Dq * 2);
    u16*      xrb    = (u16*)alloc((size_t)Lq * 3072 * 2);
    u16*      ubf    = (u16*)alloc((size_t)Lq * DIN * 2);
    float*    xdbl   = (float*)alloc((size_t)Lq * 128 * 4);
    u16*      deltab = (u16*)alloc((size_t)Lq * DIN * 2);
    float*    chA    = (float*)alloc((size_t)NCH * DIN * NST * 4);
    float*    chX    = (float*)alloc((size_t)NCH * DIN * NST * 4);
    u16*      ybf    = (u16*)alloc((size_t)Lq * DIN * 2);
    (void)ws_size; (void)in_sizes; (void)n_in; (void)out_size;

    // 1. prep: weight transposes + rmsnorm + xdbl zero-init
    TD t0{W_in,  WinT,  768, 3072,  768, 3072, 96,    0};
    TD t1{W_out, WoutT, 1536, 768, 1536,  768, 24, 2304};
    TD t2{W_x,   WxT,  1536,   80, 1536,  128,  4, 3456};
    TD t3{W_dt,  WdtT,   48, 1536,   64, 1536, 48, 3648};
    prep<<<3744 + Lq, 256, 0, stream>>>(t0, t1, t2, t3, x, norm_w, xn, xdbl);

    // 2. GEMM1: xn(2048x768) @ W_in -> xrb (bf16)
    gemm_nt<128, 128, 3><<<dim3(3072 / 128, Lq / 128), 256, 0, stream>>>(
        xn, nullptr, WinT, nullptr, xrb, nullptr, nullptr, Lq, 3072, 768, 768);

    // 3. depthwise conv + silu -> ubf
    conv_silu<<<(Lq * DIN / 8) / 256, 256, 0, stream>>>(xrb, conv_w, conv_b, ubf);

    // 4. GEMM2: ubf @ W_x(->128) -> xdbl f32, split-K=4 + atomicAdd (256 blocks)
    gemm_nt<64, 64, 2><<<dim3(128 / 64, Lq / 64, 4), 256, 0, stream>>>(
        ubf, nullptr, WxT, xdbl, nullptr, nullptr, nullptr, Lq, 128, DIN, 384);

    // 5. delta GEMM (K=64, single K-step): A = xdbl f32 (cols 0..63; W_dt^T rows 48..63
    //    are zero so the B(48..63) contamination cols contribute nothing): softplus -> deltab
    gemm_nt<128, 128, 4, true><<<dim3(1536 / 128, Lq / 128), 256, 0, stream>>>(
        nullptr, xdbl, WdtT, nullptr, deltab, nullptr, b_dt, Lq, DIN, 64, 64);

    // 6-8. selective scan (3-pass chunked, plain cached mem ops) + gate -> ybf
    scan_p1<<<dim3(NCH, DIN / 256), 256, 0, stream>>>(deltab, ubf, xdbl, A_log, chA, chX);
    scan_p2<<<96, 256, 0, stream>>>(chA, chX);
    scan_p3<<<dim3(NCH, DIN / 256), 256, 0, stream>>>(deltab, ubf, xdbl, A_log, chA, Dp, xrb, ybf);

    // 9. GEMM3: ybf @ W_out + x -> out
    gemm_nt<128, 64, 0><<<dim3(Dq / 64, Lq / 128), 256, 0, stream>>>(
        ybf, nullptr, WoutT, out, nullptr, x, nullptr, Lq, Dq, DIN, DIN);
}

// Round 8
// 207.611 us; speedup vs baseline: 4.2949x; 1.0932x over previous
//
#include <hip/hip_runtime.h>
#include <hip/hip_bf16.h>

typedef unsigned short u16;
typedef __bf16 bfx8 __attribute__((ext_vector_type(8)));
typedef float fx4 __attribute__((ext_vector_type(4)));
typedef unsigned short ushort8 __attribute__((ext_vector_type(8)));

#define DEV __device__ __forceinline__

static constexpr int Lq = 2048, Dq = 768, DIN = 1536, NST = 16;
static constexpr int NCH = 64, LC = 32;            // scan chunks: 64 x 32 = 2048

DEV u16 f2bf(float x) {
    union { float f; unsigned u; } v; v.f = x;
    unsigned r = v.u + 0x7fff + ((v.u >> 16) & 1);
    return (u16)(r >> 16);
}
DEV float bf2f(u16 v) {
    union { unsigned u; float f; } w; w.u = ((unsigned)v) << 16; return w.f;
}
// async 16B global->LDS (wave-uniform LDS base + lane*16, per-lane global addr)
DEV void gll16(const u16* g, u16* l) {
    __builtin_amdgcn_global_load_lds(
        (const __attribute__((address_space(1))) unsigned int*)g,
        (__attribute__((address_space(3))) unsigned int*)l, 16, 0, 0);
}

// ---------------- prep: 4x transpose+cast + rmsnorm + xdbl zero-init ----------
struct TD { const float* src; u16* dst; int R, C, Rp, Cp, nbx, blk0; };

__global__ __launch_bounds__(256) void prep(TD t0, TD t1, TD t2, TD t3,
                                            const float* __restrict__ x,
                                            const float* __restrict__ nw,
                                            u16* __restrict__ xn,
                                            float* __restrict__ xdbl) {
    __shared__ float tile[32][33];
    __shared__ float wsum[4];
    int b = blockIdx.x;
    if (b < 3744) {
        TD td = t0;
        if (b >= t3.blk0) td = t3; else if (b >= t2.blk0) td = t2; else if (b >= t1.blk0) td = t1;
        int local = b - td.blk0;
        int c0 = (local % td.nbx) * 32, r0 = (local / td.nbx) * 32;
        int tx = threadIdx.x & 31, ty = threadIdx.x >> 5;   // 32 x 8
        #pragma unroll
        for (int i = ty; i < 32; i += 8) {
            int r = r0 + i, c = c0 + tx;
            tile[i][tx] = (r < td.R && c < td.C) ? td.src[(size_t)r * td.C + c] : 0.f;
        }
        __syncthreads();
        #pragma unroll
        for (int i = ty; i < 32; i += 8) {
            int c = c0 + i, r = r0 + tx;
            if (c < td.Cp && r < td.Rp) td.dst[(size_t)c * td.Rp + r] = f2bf(tile[tx][i]);
        }
    } else {
        int t = b - 3744;
        // zero xdbl row t (split-K GEMM2 accumulates into it atomically)
        if (threadIdx.x < 128) xdbl[(size_t)t * 128 + threadIdx.x] = 0.f;
        const float* row = x + (size_t)t * Dq;
        float ss = 0.f;
        for (int i = threadIdx.x; i < Dq; i += 256) { float a = row[i]; ss += a * a; }
        #pragma unroll
        for (int o = 32; o > 0; o >>= 1) ss += __shfl_xor(ss, o, 64);
        if ((threadIdx.x & 63) == 0) wsum[threadIdx.x >> 6] = ss;
        __syncthreads();
        ss = wsum[0] + wsum[1] + wsum[2] + wsum[3];
        float scale = rsqrtf(ss * (1.f / Dq) + 1e-5f);
        for (int i = threadIdx.x; i < Dq; i += 256)
            xn[(size_t)t * Dq + i] = f2bf(row[i] * scale * nw[i]);
    }
}

// ---------------- generic NT bf16 MFMA GEMM, BK=64, gll staging + XOR-16B swizzle -------
// A: M x K bf16 row-major (or, if AF32, Af: M x 128 f32, cols kt.. used). BT: N x K bf16.
// EPI 0: C=acc(+R). EPI 2: atomicAdd(C, acc). EPI 3: Cb=bf16(acc).
// EPI 4: Cb=bf16(softplus(acc+bias[col])).
template<int BM, int BN, int EPI, bool AF32 = false>
__global__ __launch_bounds__(256) void gemm_nt(const u16* __restrict__ A,
                                               const float* __restrict__ Af,
                                               const u16* __restrict__ BT,
                                               float* __restrict__ C, u16* __restrict__ Cb,
                                               const float* __restrict__ R,
                                               const float* __restrict__ bias,
                                               int M, int N, int K, int kLen) {
    constexpr int BK = 64;
    constexpr int WM = BM / 2, WN = BN / 2, MI = WM / 16, NI = WN / 16;
    __shared__ u16 As[BM * BK];
    __shared__ u16 Bs[BN * BK];
    const int tid = threadIdx.x, lane = tid & 63, wid = tid >> 6;
    const int wr = wid >> 1, wc = wid & 1;
    const int bm0 = blockIdx.y * BM, bn0 = blockIdx.x * BN;
    const int k0 = blockIdx.z * kLen;
    const int li = lane & 15, g = lane >> 4;

    fx4 acc[MI][NI];
    #pragma unroll
    for (int mi = 0; mi < MI; mi++)
        #pragma unroll
        for (int ni = 0; ni < NI; ni++)
            #pragma unroll
            for (int q = 0; q < 4; q++) acc[mi][ni][q] = 0.f;

    for (int kt = k0; kt < k0 + kLen; kt += BK) {
        // stage: 16B granule c -> LDS linear; global granule pre-XORed so that
        // LDS(row, j) holds global granule j^(row&7)  (involution, rule 21)
        if constexpr (AF32) {
            // A from f32 source (row stride 128 f32): reg-stage + cvt + ds_write,
            // same granule->swizzle mapping as the gll16 path.
            #pragma unroll
            for (int i = 0; i < (BM * 8) / 256; i++) {
                int c = i * 256 + tid;
                int row = c >> 3, g16 = (c & 7) ^ (row & 7);
                const float* src = Af + (size_t)(bm0 + row) * 128 + kt + g16 * 8;
                float4 a0 = *(const float4*)src;
                float4 a1 = *(const float4*)(src + 4);
                ushort8 o;
                o[0] = f2bf(a0.x); o[1] = f2bf(a0.y); o[2] = f2bf(a0.z); o[3] = f2bf(a0.w);
                o[4] = f2bf(a1.x); o[5] = f2bf(a1.y); o[6] = f2bf(a1.z); o[7] = f2bf(a1.w);
                *(ushort8*)(&As[c * 8]) = o;
            }
        } else {
            #pragma unroll
            for (int i = 0; i < (BM * 8) / 256; i++) {
                int cb = i * 256 + wid * 64;
                int c = cb + lane;
                int row = c >> 3, g16 = (c & 7) ^ (row & 7);
                gll16(A + (size_t)(bm0 + row) * K + kt + g16 * 8, &As[cb * 8]);
            }
        }
        #pragma unroll
        for (int i = 0; i < (BN * 8) / 256; i++) {
            int cb = i * 256 + wid * 64;
            int c = cb + lane;
            int row = c >> 3, g16 = (c & 7) ^ (row & 7);
            gll16(BT + (size_t)(bn0 + row) * K + kt + g16 * 8, &Bs[cb * 8]);
        }
        __syncthreads();
        bfx8 af[MI][2], bfr[NI][2];
        #pragma unroll
        for (int mi = 0; mi < MI; mi++) {
            int row = wr * WM + mi * 16 + li;
            #pragma unroll
            for (int ks = 0; ks < 2; ks++)
                af[mi][ks] = *(const bfx8*)&As[row * BK + (((ks * 4 + g) ^ (row & 7)) * 8)];
        }
        #pragma unroll
        for (int ni = 0; ni < NI; ni++) {
            int row = wc * WN + ni * 16 + li;
            #pragma unroll
            for (int ks = 0; ks < 2; ks++)
                bfr[ni][ks] = *(const bfx8*)&Bs[row * BK + (((ks * 4 + g) ^ (row & 7)) * 8)];
        }
        #pragma unroll
        for (int ks = 0; ks < 2; ks++)
            #pragma unroll
            for (int mi = 0; mi < MI; mi++)
                #pragma unroll
                for (int ni = 0; ni < NI; ni++)
                    acc[mi][ni] = __builtin_amdgcn_mfma_f32_16x16x32_bf16(
                        af[mi][ks], bfr[ni][ks], acc[mi][ni], 0, 0, 0);
        __syncthreads();
    }

    #pragma unroll
    for (int mi = 0; mi < MI; mi++)
        #pragma unroll
        for (int ni = 0; ni < NI; ni++)
            #pragma unroll
            for (int q = 0; q < 4; q++) {
                int row = bm0 + wr * WM + mi * 16 + g * 4 + q;
                int col = bn0 + wc * WN + ni * 16 + li;
                size_t idx = (size_t)row * N + col;
                float v = acc[mi][ni][q];
                if constexpr (EPI == 0) {
                    if (R) v += R[idx];
                    C[idx] = v;
                } else if constexpr (EPI == 2) {
                    atomicAdd(&C[idx], v);
                } else if constexpr (EPI == 3) {
                    Cb[idx] = f2bf(v);
                } else if constexpr (EPI == 4) {
                    v += bias[col];
                    Cb[idx] = f2bf((v > 20.f) ? v : log1pf(__expf(v)));
                }
            }
}

// ---------------- depthwise causal conv (K=4) + bias + SiLU, 8-wide bf16 ----------------
__global__ __launch_bounds__(256) void conv_silu(const u16* __restrict__ xrb,
                                                 const float* __restrict__ cw,
                                                 const float* __restrict__ cb,
                                                 u16* __restrict__ ubf) {
    int i = blockIdx.x * 256 + threadIdx.x;            // one 8-group
    int t = i / (DIN / 8), d8 = (i - t * (DIN / 8)) * 8;
    float acc[8];
    #pragma unroll
    for (int j = 0; j < 8; j++) acc[j] = cb[d8 + j];
    #pragma unroll
    for (int k = 0; k < 4; k++) {
        int tt = t - 3 + k;
        if (tt < 0) continue;
        ushort8 xv = *(const ushort8*)(xrb + (size_t)tt * (2 * DIN) + d8);
        #pragma unroll
        for (int j = 0; j < 8; j++) acc[j] = fmaf(bf2f(xv[j]), cw[k * DIN + d8 + j], acc[j]);
    }
    ushort8 o;
    #pragma unroll
    for (int j = 0; j < 8; j++) {
        float s = acc[j] / (1.f + __expf(-acc[j]));
        o[j] = f2bf(s);
    }
    *(ushort8*)(ubf + (size_t)i * 8) = o;
}

// ---------------- selective scan, 3-pass chunked; chX/init layout [n][chunk][d] ----------
// pass 1: local chunk scan from 0; store end-state (chX) and delta-sum (sdl) per (c,d).
__global__ __launch_bounds__(256) void scan_p1(const u16* __restrict__ deltab, const u16* __restrict__ ubf,
                                               const float* __restrict__ xdbl, const float* __restrict__ A_log,
                                               float* __restrict__ sdlb, float* __restrict__ chX) {
    const int c = blockIdx.x;
    const int d = blockIdx.y * 256 + threadIdx.x;
    float An[NST];
    #pragma unroll
    for (int i = 0; i < 4; i++) {
        float4 a = *(const float4*)(A_log + (size_t)d * NST + i * 4);
        An[i * 4 + 0] = -__expf(a.x); An[i * 4 + 1] = -__expf(a.y);
        An[i * 4 + 2] = -__expf(a.z); An[i * 4 + 3] = -__expf(a.w);
    }
    float s[NST];
    #pragma unroll
    for (int n = 0; n < NST; n++) s[n] = 0.f;
    float sdl = 0.f;
    const int t0 = c * LC;
    for (int tt = 0; tt < LC; tt++) {
        int t = t0 + tt;
        float dl = bf2f(deltab[(size_t)t * DIN + d]);
        float uu = bf2f(ubf[(size_t)t * DIN + d]);
        float dlu = dl * uu;
        #pragma unroll
        for (int i = 0; i < 4; i++) {
            float4 b = *(const float4*)(xdbl + (size_t)t * 128 + 48 + i * 4);
            float dA0 = __expf(dl * An[i*4+0]); s[i*4+0] = fmaf(dA0, s[i*4+0], dlu * b.x);
            float dA1 = __expf(dl * An[i*4+1]); s[i*4+1] = fmaf(dA1, s[i*4+1], dlu * b.y);
            float dA2 = __expf(dl * An[i*4+2]); s[i*4+2] = fmaf(dA2, s[i*4+2], dlu * b.z);
            float dA3 = __expf(dl * An[i*4+3]); s[i*4+3] = fmaf(dA3, s[i*4+3], dlu * b.w);
        }
        sdl += dl;
    }
    #pragma unroll
    for (int n = 0; n < NST; n++)
        chX[(size_t)n * (NCH * DIN) + (size_t)c * DIN + d] = s[n];
    sdlb[(size_t)c * DIN + d] = sdl;
}

// pass 2: cross-chunk serial combine per (n,d); A-product rebuilt from sdl;
//         chunk-initial state written into init.
__global__ __launch_bounds__(256) void scan_p2(float* __restrict__ init, const float* __restrict__ chX,
                                               const float* __restrict__ sdlb,
                                               const float* __restrict__ A_log) {
    int fid = blockIdx.x;                 // 96 blocks: n = fid/6, dblk = fid%6
    int n = fid / 6, dd = (fid % 6) * 256 + threadIdx.x;
    float An = -__expf(A_log[(size_t)dd * NST + n]);
    size_t base = (size_t)n * (NCH * DIN) + dd;
    float s2 = 0.f;
    for (int cc = 0; cc < NCH; cc++) {
        size_t idx = base + (size_t)cc * DIN;
        float a = __expf(An * sdlb[(size_t)cc * DIN + dd]);
        float xv = chX[idx];
        init[idx] = s2;                   // becomes init-state for chunk cc
        s2 = fmaf(a, s2, xv);
    }
}

// pass 3: rescan with init, in-register n-reduction, gate -> ybf.
__global__ __launch_bounds__(256) void scan_p3(const u16* __restrict__ deltab, const u16* __restrict__ ubf,
                                               const float* __restrict__ xdbl, const float* __restrict__ A_log,
                                               const float* __restrict__ init, const float* __restrict__ Dp,
                                               const u16* __restrict__ xrb, u16* __restrict__ ybf) {
    const int c = blockIdx.x;
    const int d = blockIdx.y * 256 + threadIdx.x;
    float An[NST];
    #pragma unroll
    for (int i = 0; i < 4; i++) {
        float4 a = *(const float4*)(A_log + (size_t)d * NST + i * 4);
        An[i * 4 + 0] = -__expf(a.x); An[i * 4 + 1] = -__expf(a.y);
        An[i * 4 + 2] = -__expf(a.z); An[i * 4 + 3] = -__expf(a.w);
    }
    float s[NST];
    #pragma unroll
    for (int n = 0; n < NST; n++)
        s[n] = init[(size_t)n * (NCH * DIN) + (size_t)c * DIN + d];
    float Dpd = Dp[d];
    const int t0 = c * LC;
    for (int tt = 0; tt < LC; tt++) {
        int t = t0 + tt;
        float dl = bf2f(deltab[(size_t)t * DIN + d]);
        float uu = bf2f(ubf[(size_t)t * DIN + d]);
        float dlu = dl * uu;
        float p = 0.f;
        #pragma unroll
        for (int i = 0; i < 4; i++) {
            float4 b  = *(const float4*)(xdbl + (size_t)t * 128 + 48 + i * 4);
            float4 cc = *(const float4*)(xdbl + (size_t)t * 128 + 64 + i * 4);
            float dA0 = __expf(dl * An[i*4+0]); s[i*4+0] = fmaf(dA0, s[i*4+0], dlu * b.x); p = fmaf(s[i*4+0], cc.x, p);
            float dA1 = __expf(dl * An[i*4+1]); s[i*4+1] = fmaf(dA1, s[i*4+1], dlu * b.y); p = fmaf(s[i*4+1], cc.y, p);
            float dA2 = __expf(dl * An[i*4+2]); s[i*4+2] = fmaf(dA2, s[i*4+2], dlu * b.z); p = fmaf(s[i*4+2], cc.z, p);
            float dA3 = __expf(dl * An[i*4+3]); s[i*4+3] = fmaf(dA3, s[i*4+3], dlu * b.w); p = fmaf(s[i*4+3], cc.w, p);
        }
        float res = bf2f(xrb[(size_t)t * (2 * DIN) + DIN + d]);
        float y = fmaf(uu, Dpd, p) * (res / (1.f + __expf(-res)));
        ybf[(size_t)t * DIN + d] = f2bf(y);
    }
}

extern "C" void kernel_launch(void* const* d_in, const int* in_sizes, int n_in,
                              void* d_out, int out_size, void* d_ws, size_t ws_size,
                              hipStream_t stream) {
    const float* x      = (const float*)d_in[0];
    const float* norm_w = (const float*)d_in[1];
    const float* W_in   = (const float*)d_in[2];
    const float* conv_w = (const float*)d_in[3];
    const float* conv_b = (const float*)d_in[4];
    const float* W_x    = (const float*)d_in[5];
    const float* W_dt   = (const float*)d_in[6];
    const float* b_dt   = (const float*)d_in[7];
    const float* A_log  = (const float*)d_in[8];
    const float* Dp     = (const float*)d_in[9];
    const float* W_out  = (const float*)d_in[10];
    float* out = (float*)d_out;

    char* wp = (char*)d_ws;
    auto alloc = [&](size_t bytes) { char* p = wp; wp += (bytes + 255) & ~(size_t)255; return p; };
    u16*      WinT   = (u16*)alloc((size_t)3072 * 768 * 2);
    u16*      WoutT  = (u16*)alloc((size_t)768 * 1536 * 2);
    u16*      WxT    = (u16*)alloc((size_t)128 * 1536 * 2);
    u16*      WdtT   = (u16*)alloc((size_t)1536 * 64 * 2);
    u16*      xn     = (u16*)alloc((size_t)Lq * Dq * 2);
    u16*      xrb    = (u16*)alloc((size_t)Lq * 3072 * 2);
    u16*      ubf    = (u16*)alloc((size_t)Lq * DIN * 2);
    float*    xdbl   = (float*)alloc((size_t)Lq * 128 * 4);
    u16*      deltab = (u16*)alloc((size_t)Lq * DIN * 2);
    float*    initS  = (float*)alloc((size_t)NCH * DIN * NST * 4);
    float*    chX    = (float*)alloc((size_t)NCH * DIN * NST * 4);
    float*    sdlb   = (float*)alloc((size_t)NCH * DIN * 4);
    u16*      ybf    = (u16*)alloc((size_t)Lq * DIN * 2);
    (void)ws_size; (void)in_sizes; (void)n_in; (void)out_size;

    // 1. prep: weight transposes + rmsnorm + xdbl zero-init
    TD t0{W_in,  WinT,  768, 3072,  768, 3072, 96,    0};
    TD t1{W_out, WoutT, 1536, 768, 1536,  768, 24, 2304};
    TD t2{W_x,   WxT,  1536,   80, 1536,  128,  4, 3456};
    TD t3{W_dt,  WdtT,   48, 1536,   64, 1536, 48, 3648};
    prep<<<3744 + Lq, 256, 0, stream>>>(t0, t1, t2, t3, x, norm_w, xn, xdbl);

    // 2. GEMM1: xn(2048x768) @ W_in -> xrb (bf16). 64x128 tile -> 768 blocks (3/CU).
    gemm_nt<64, 128, 3><<<dim3(3072 / 128, Lq / 64), 256, 0, stream>>>(
        xn, nullptr, WinT, nullptr, xrb, nullptr, nullptr, Lq, 3072, 768, 768);

    // 3. depthwise conv + silu -> ubf
    conv_silu<<<(Lq * DIN / 8) / 256, 256, 0, stream>>>(xrb, conv_w, conv_b, ubf);

    // 4. GEMM2: ubf @ W_x(->128) -> xdbl f32, split-K=4 + atomicAdd (256 blocks)
    gemm_nt<64, 64, 2><<<dim3(128 / 64, Lq / 64, 4), 256, 0, stream>>>(
        ubf, nullptr, WxT, xdbl, nullptr, nullptr, nullptr, Lq, 128, DIN, 384);

    // 5. delta GEMM (K=64, single K-step): A = xdbl f32 (cols 0..63; W_dt^T rows 48..63
    //    zero). 64x128 tile -> 384 blocks. softplus -> deltab
    gemm_nt<64, 128, 4, true><<<dim3(1536 / 128, Lq / 64), 256, 0, stream>>>(
        nullptr, xdbl, WdtT, nullptr, deltab, nullptr, b_dt, Lq, DIN, 64, 64);

    // 6-8. selective scan (3-pass chunked) + gate -> ybf
    scan_p1<<<dim3(NCH, DIN / 256), 256, 0, stream>>>(deltab, ubf, xdbl, A_log, sdlb, chX);
    scan_p2<<<96, 256, 0, stream>>>(initS, chX, sdlb, A_log);
    scan_p3<<<dim3(NCH, DIN / 256), 256, 0, stream>>>(deltab, ubf, xdbl, A_log, initS, Dp, xrb, ybf);

    // 9. GEMM3: ybf @ W_out + x -> out. 64x64 tile -> 384 blocks.
    gemm_nt<64, 64, 0><<<dim3(Dq / 64, Lq / 64), 256, 0, stream>>>(
        ybf, nullptr, WoutT, out, nullptr, x, nullptr, Lq, Dq, DIN, DIN);
}